// Round 1
// 242.726 us; speedup vs baseline: 1.0383x; 1.0383x over previous
//
#include <hip/hip_runtime.h>

#define B_  8
#define C_  256
#define O_  256
#define H_  56
#define W_  56
#define HW_ 3136
#define KK_ 9
#define CK_ 2304   // C_*KK_
#define NKC 72     // K-chunks of 32

typedef __bf16    bf16x8 __attribute__((ext_vector_type(8)));
typedef float     f32x4  __attribute__((ext_vector_type(4)));

// async 16B/lane global->LDS: lds base wave-uniform; HW adds lane*16.
__device__ __forceinline__ void async16(const void* gsrc_lane, void* lds_uniform) {
    __builtin_amdgcn_global_load_lds(
        (const __attribute__((address_space(1))) unsigned int*)gsrc_lane,
        (__attribute__((address_space(3))) unsigned int*)lds_uniform, 16, 0, 0);
}

// XOR chunk swizzle: logical 16B-chunk q of row r stored at q ^ swz4(r).
// Makes stride-64B-row b128 frag reads 2-way bank-aliased (= free).
__device__ __forceinline__ int swz4(int r) { return (r & 3) ^ ((r >> 2) & 3); }

__device__ __forceinline__ float blo(unsigned u) {
    return __builtin_bit_cast(float, u << 16);
}
__device__ __forceinline__ float bhi(unsigned u) {
    return __builtin_bit_cast(float, u & 0xffff0000u);
}
__device__ __forceinline__ unsigned pkbf(float lo, float hi) {
    unsigned short a = __builtin_bit_cast(unsigned short, (__bf16)lo);
    unsigned short b = __builtin_bit_cast(unsigned short, (__bf16)hi);
    return (unsigned)a | ((unsigned)b << 16);
}

// ---------------------------------------------------------------------------
// Kernel 1: wA[kc][m=256][32] bf16, tap-major K (g=kc*32+kl -> tap=g>>8,
// c=g&255), XOR chunk swizzle baked into the global image. 1.18 MB.
// ---------------------------------------------------------------------------
__global__ __launch_bounds__(256) void k_buildA(const float* __restrict__ w,
                                                unsigned short* __restrict__ wA) {
    int d  = blockIdx.x * 256 + threadIdx.x;   // exact 2304*256
    int kc = d >> 13;
    int rd = d & 8191;
    int m  = rd >> 5;
    int pos = rd & 31;
    int q  = (pos >> 3) ^ swz4(m);
    int kl = q * 8 + (pos & 7);
    int gk = kc * 32 + kl;
    int tap = gk >> 8, c = gk & 255;
    __bf16 v = (__bf16)w[m * CK_ + c * KK_ + tap];
    wA[d] = __builtin_bit_cast(unsigned short, v);
}

// ---------------------------------------------------------------------------
// Kernel 2: x NCHW f32 -> xT NHWC bf16 (12.85 MB). 64hw x 64c LDS tiles,
// both sides coalesced; +1 pad makes the transposed read 2-way (free).
// ---------------------------------------------------------------------------
__global__ __launch_bounds__(256) void k_transx(const float* __restrict__ x,
                                                unsigned short* __restrict__ xT) {
    __shared__ float s[64][65];
    int bt   = blockIdx.x;            // 8 * 49 * 4
    int c64  = bt & 3;
    int hw64 = (bt >> 2) % 49;
    int b    = bt / 196;
    int tx = threadIdx.x & 63;
    int ty = threadIdx.x >> 6;
#pragma unroll
    for (int i = 0; i < 16; ++i)
        s[i * 4 + ty][tx] =
            x[((size_t)(b * 256 + c64 * 64 + i * 4 + ty)) * HW_ + hw64 * 64 + tx];
    __syncthreads();
#pragma unroll
    for (int i = 0; i < 16; ++i) {
        float v = s[tx][i * 4 + ty];
        xT[((size_t)b * HW_ + hw64 * 64 + i * 4 + ty) * 256 + c64 * 64 + tx] =
            __builtin_bit_cast(unsigned short, (__bf16)v);
    }
}

// ---------------------------------------------------------------------------
// Kernel 3a: offset conv partials. C split into 4 slices of 64 -> grid 1568
// (6.1 blocks/CU, ~24 waves/CU). Block = 512 thr = 64 pos x 8 c-subgroups
// of 8 ch; LDS-reduce 8 subgroups. part[sl][b][18][HW] fp32.
// ---------------------------------------------------------------------------
__global__ __launch_bounds__(512) void k_offc1(const float* __restrict__ x,
                                               const float* __restrict__ w_off,
                                               float* __restrict__ part) {
    __shared__ float partial[8][64][18];      // 36864 B
    int t  = threadIdx.x;
    int p  = t & 63;
    int cg = __builtin_amdgcn_readfirstlane(t >> 6);
    int blk  = blockIdx.x;                    // 1568 = 392 units * 4 slices
    int sl   = blk & 3;
    int un   = blk >> 2;
    int b    = un / 49;
    int pos0 = (un % 49) * 64;
    int pos  = pos0 + p;
    int h = pos / W_;
    int w = pos % W_;
    const float* xb = x + (size_t)b * C_ * HW_;

    float acc[18];
#pragma unroll
    for (int i = 0; i < 18; ++i) acc[i] = 0.f;

    for (int cc = 0; cc < 8; ++cc) {
        int c = sl * 64 + cg * 8 + cc;
        const float* xp = xb + c * HW_;
        float v[9];
#pragma unroll
        for (int dh = -1; dh <= 1; ++dh)
#pragma unroll
            for (int dw = -1; dw <= 1; ++dw) {
                int hh = h + dh, ww = w + dw;
                bool ok = (hh >= 0) & (hh < H_) & (ww >= 0) & (ww < W_);
                v[(dh + 1) * 3 + dw + 1] = ok ? xp[hh * W_ + ww] : 0.f;
            }
        const float* wc = w_off + c * KK_;
#pragma unroll
        for (int oc = 0; oc < 18; ++oc) {
            const float* wr = wc + oc * CK_;  // wave-uniform -> s_load
#pragma unroll
            for (int k = 0; k < KK_; ++k)
                acc[oc] = fmaf(v[k], wr[k], acc[oc]);
        }
    }
#pragma unroll
    for (int oc = 0; oc < 18; ++oc) partial[cg][p][oc] = acc[oc];
    __syncthreads();

    float* po = part + (size_t)sl * (B_ * 18 * HW_);
    for (int e = t; e < 64 * 18; e += 512) {
        int oc = e >> 6;
        int pp = e & 63;
        float s = 0.f;
#pragma unroll
        for (int g = 0; g < 8; ++g) s += partial[g][pp][oc];
        po[((size_t)b * 18 + oc) * HW_ + pos0 + pp] = s;
    }
}

// ---------------------------------------------------------------------------
// Kernel 3b: sum 4 slices + bias -> off. Pure streaming (9 MB), ~2 us.
// ---------------------------------------------------------------------------
__global__ __launch_bounds__(256) void k_offc2(const float* __restrict__ part,
                                               const float* __restrict__ b_off,
                                               float* __restrict__ off) {
    int i = blockIdx.x * 256 + threadIdx.x;   // exact 451584
    const int NP = B_ * 18 * HW_;
    int oc = (i / HW_) % 18;
    off[i] = part[i] + part[i + NP] + part[i + 2 * NP] + part[i + 3 * NP]
           + b_off[oc];
}

// ---------------------------------------------------------------------------
// Kernel 4: gather from NHWC xT -> V[u][kc][n=64][32] bf16 (swizzled GEMM
// image). Block = (unit, ch-half of 128), 256 threads = 64 n x 4 tc.
// Per (tap, cb): 4 coalesced dwordx4 corner loads (8 ch), f32 bilinear, one
// 16B store. Corner addresses clamped + weight zeroed (exact ref semantics).
// Block->XCD mapping identical to k_gemm so V stays in the local L2.
// ---------------------------------------------------------------------------
__global__ __launch_bounds__(256) void k_gather(const unsigned short* __restrict__ xT,
                                                const float* __restrict__ off,
                                                unsigned short* __restrict__ V,
                                                int unit0, int upc) {
    __shared__ int   s_id[KK_][64][4];
    __shared__ float s_w[KK_][64][4];

    int xk  = blockIdx.x;
    int u   = (xk >> 4) * 8 + (xk & 7);
    int chh = (xk >> 3) & 1;
    if (u >= upc) return;
    int g    = unit0 + u;
    int b    = g / 49;
    int pos0 = (g % 49) * 64;
    int t    = threadIdx.x;

    // --- bilinear tables (byte offsets into NHWC plane, 4 weights) ---
    for (int e = t; e < KK_ * 64; e += 256) {
        int k = e >> 6, n = e & 63;
        int pos = pos0 + n;
        int h = pos / W_, w = pos % W_;
        float dy = off[((size_t)b * 18 + 2 * k) * HW_ + pos];
        float dx = off[((size_t)b * 18 + 2 * k + 1) * HW_ + pos];
        float py = (float)(h + k / 3 - 1) + dy;
        float px = (float)(w + k % 3 - 1) + dx;
        float y0f = floorf(py), x0f = floorf(px);
        float fy = py - y0f, fx = px - x0f;
        int y0 = (int)y0f, x0 = (int)x0f;
        int y1 = y0 + 1,   x1 = x0 + 1;
        float oy0 = (y0 >= 0 && y0 < H_) ? 1.f : 0.f;
        float oy1 = (y1 >= 0 && y1 < H_) ? 1.f : 0.f;
        float ox0 = (x0 >= 0 && x0 < W_) ? 1.f : 0.f;
        float ox1 = (x1 >= 0 && x1 < W_) ? 1.f : 0.f;
        int y0c = min(max(y0, 0), H_ - 1), y1c = min(max(y1, 0), H_ - 1);
        int x0c = min(max(x0, 0), W_ - 1), x1c = min(max(x1, 0), W_ - 1);
        s_id[k][n][0] = (y0c * W_ + x0c) * 512;   // 256 ch * 2 B
        s_id[k][n][1] = (y0c * W_ + x1c) * 512;
        s_id[k][n][2] = (y1c * W_ + x0c) * 512;
        s_id[k][n][3] = (y1c * W_ + x1c) * 512;
        s_w[k][n][0] = (1.f - fy) * (1.f - fx) * oy0 * ox0;
        s_w[k][n][1] = (1.f - fy) * fx         * oy0 * ox1;
        s_w[k][n][2] = fy * (1.f - fx)         * oy1 * ox0;
        s_w[k][n][3] = fy * fx                 * oy1 * ox1;
    }
    __syncthreads();

    int n  = t >> 2;
    int tc = t & 3;
    int sc = tc ^ swz4(n);                      // swizzled chunk for stores
    const char* xb = (const char*)(xT + (size_t)b * HW_ * 256);
    unsigned short* Vu = V + (size_t)u * NKC * 2048;   // 64*32 per kc

#pragma unroll
    for (int tap = 0; tap < KK_; ++tap) {
        int4  id = *(const int4*)s_id[tap][n];
        float4 wg = *(const float4*)s_w[tap][n];
#pragma unroll
        for (int cb = 0; cb < 4; ++cb) {
            int kc   = tap * 8 + chh * 4 + cb;
            int boff = (chh * 128 + cb * 32 + tc * 8) * 2;
            const char* p = xb + boff;
            uint4 c00 = *(const uint4*)(p + id.x);
            uint4 c01 = *(const uint4*)(p + id.y);
            uint4 c10 = *(const uint4*)(p + id.z);
            uint4 c11 = *(const uint4*)(p + id.w);
            uint4 o;
            {
                float lo, hi;
                lo = wg.x*blo(c00.x) + wg.y*blo(c01.x) + wg.z*blo(c10.x) + wg.w*blo(c11.x);
                hi = wg.x*bhi(c00.x) + wg.y*bhi(c01.x) + wg.z*bhi(c10.x) + wg.w*bhi(c11.x);
                o.x = pkbf(lo, hi);
                lo = wg.x*blo(c00.y) + wg.y*blo(c01.y) + wg.z*blo(c10.y) + wg.w*blo(c11.y);
                hi = wg.x*bhi(c00.y) + wg.y*bhi(c01.y) + wg.z*bhi(c10.y) + wg.w*bhi(c11.y);
                o.y = pkbf(lo, hi);
                lo = wg.x*blo(c00.z) + wg.y*blo(c01.z) + wg.z*blo(c10.z) + wg.w*blo(c11.z);
                hi = wg.x*bhi(c00.z) + wg.y*bhi(c01.z) + wg.z*bhi(c10.z) + wg.w*bhi(c11.z);
                o.z = pkbf(lo, hi);
                lo = wg.x*blo(c00.w) + wg.y*blo(c01.w) + wg.z*blo(c10.w) + wg.w*blo(c11.w);
                hi = wg.x*bhi(c00.w) + wg.y*bhi(c01.w) + wg.z*bhi(c10.w) + wg.w*bhi(c11.w);
                o.w = pkbf(lo, hi);
            }
            *(uint4*)(Vu + ((size_t)kc * 64 + n) * 32 + sc * 8) = o;
        }
    }
}

// ---------------------------------------------------------------------------
// Kernel 5: bf16 MFMA GEMM, 256(O) x 64(n), K=2304 (one block per unit,
// blockIdx=u keeps u%8 XCD co-location with k_gather). 4 waves, wave tile
// 64x64 -> per kc: 8 ds_read_b128 feed 16 MFMA (512 LDS-B/MFMA).
// 3-stage circular LDS (60 KB -> 2 blocks/CU), counted vmcnt(5) + raw
// s_barrier (ONE barrier/stage, never vmcnt(0) in steady state), prefetch
// issued 2 stages ahead right after the barrier, setprio around MFMA.
// Race-safety: each wave's vmcnt covers its own disjoint LDS slice; buffer
// (s+2)%3 was last read at stage s-1, whose ds_reads retired before every
// wave passed the stage-s barrier (data-dep through their MFMAs).
// ---------------------------------------------------------------------------
template<int RB, int PF, bool DOPF, bool LAST>
__device__ __forceinline__ void gemm_stage(int s,
                                           const char* gA0, const char* gB0,
                                           __bf16 (*s_a)[8192], __bf16 (*s_b)[2048],
                                           int wv, int lid, int quad, int swz,
                                           int lo, f32x4 (&acc)[4][4]) {
    if constexpr (LAST) {
        asm volatile("s_waitcnt vmcnt(0)" ::: "memory");
    } else {
        asm volatile("s_waitcnt vmcnt(5)" ::: "memory");
    }
    __builtin_amdgcn_s_barrier();
    asm volatile("" ::: "memory");
    __builtin_amdgcn_sched_barrier(0);

    if constexpr (DOPF) {   // prefetch stage s+2 into buffer PF
        const char* ga = gA0 + (size_t)(s + 2) * 16384;
        const char* gb = gB0 + (size_t)(s + 2) * 4096;
        char* la = (char*)s_a[PF];
        char* lb = (char*)s_b[PF];
#pragma unroll
        for (int j = 0; j < 4; ++j)
            async16(ga + wv * 4096 + j * 1024 + lo, la + wv * 4096 + j * 1024);
        async16(gb + wv * 1024 + lo, lb + wv * 1024);
    }

    const bf16x8* pa = (const bf16x8*)s_a[RB];
    const bf16x8* pbf = (const bf16x8*)s_b[RB];
    bf16x8 af[4], bv[4];
#pragma unroll
    for (int mi = 0; mi < 4; ++mi)
        af[mi] = pa[(wv * 64 + mi * 16 + lid) * 4 + (quad ^ swz)];
#pragma unroll
    for (int ni = 0; ni < 4; ++ni)
        bv[ni] = pbf[(ni * 16 + lid) * 4 + (quad ^ swz)];

    __builtin_amdgcn_s_setprio(1);
#pragma unroll
    for (int mi = 0; mi < 4; ++mi)
#pragma unroll
        for (int ni = 0; ni < 4; ++ni)
            acc[mi][ni] = __builtin_amdgcn_mfma_f32_16x16x32_bf16(
                af[mi], bv[ni], acc[mi][ni], 0, 0, 0);
    __builtin_amdgcn_s_setprio(0);
}

__global__ __launch_bounds__(256, 2) void k_gemm(const __bf16* __restrict__ V,
                                                 const __bf16* __restrict__ wA,
                                                 const float* __restrict__ b_dcn,
                                                 float* __restrict__ out,
                                                 int unit0, int upc) {
    __shared__ __bf16 s_a[3][8192];   // 3 x 16 KB (one kc: 256 m x 32 k)
    __shared__ __bf16 s_b[3][2048];   // 3 x  4 KB (one kc:  64 n x 32 k)

    int u    = blockIdx.x;            // grid = exact unit count
    int g    = unit0 + u;
    int b    = g / 49;
    int pos0 = (g % 49) * 64;

    int t    = threadIdx.x;
    int lane = t & 63;
    int wv   = t >> 6;
    int lid  = lane & 15;
    int quad = lane >> 4;
    int swz  = swz4(lid);

    f32x4 acc[4][4];
#pragma unroll
    for (int mi = 0; mi < 4; ++mi)
#pragma unroll
        for (int ni = 0; ni < 4; ++ni)
            acc[mi][ni] = (f32x4)(0.f);

    const char* gA0 = (const char*)wA;
    const char* gB0 = (const char*)V + (size_t)u * NKC * 4096;
    int lo = lane * 16;

    // prologue: stages 0,1 into buffers 0,1 (10 loads/thread outstanding)
#pragma unroll
    for (int ss = 0; ss < 2; ++ss) {
        const char* ga = gA0 + (size_t)ss * 16384;
        const char* gb = gB0 + (size_t)ss * 4096;
        char* la = (char*)s_a[ss];
        char* lb = (char*)s_b[ss];
#pragma unroll
        for (int j = 0; j < 4; ++j)
            async16(ga + wv * 4096 + j * 1024 + lo, la + wv * 4096 + j * 1024);
        async16(gb + wv * 1024 + lo, lb + wv * 1024);
    }

    // 72 kc stages; unrolled x3 so buffer indices are compile-time.
    for (int s3 = 0; s3 < 69; s3 += 3) {
        gemm_stage<0, 2, true, false>(s3,     gA0, gB0, s_a, s_b, wv, lid, quad, swz, lo, acc);
        gemm_stage<1, 0, true, false>(s3 + 1, gA0, gB0, s_a, s_b, wv, lid, quad, swz, lo, acc);
        gemm_stage<2, 1, true, false>(s3 + 2, gA0, gB0, s_a, s_b, wv, lid, quad, swz, lo, acc);
    }
    gemm_stage<0, 2, true,  false>(69, gA0, gB0, s_a, s_b, wv, lid, quad, swz, lo, acc);
    gemm_stage<1, 0, false, false>(70, gA0, gB0, s_a, s_b, wv, lid, quad, swz, lo, acc);
    gemm_stage<2, 0, false, true >(71, gA0, gB0, s_a, s_b, wv, lid, quad, swz, lo, acc);

    // epilogue: bias + store. D: col(n)=lane&15, row(m)=quad*4+reg
#pragma unroll
    for (int mi = 0; mi < 4; ++mi) {
#pragma unroll
        for (int r = 0; r < 4; ++r) {
            int m = wv * 64 + mi * 16 + quad * 4 + r;
            float bias = b_dcn[m];
            float* po = out + ((size_t)b * O_ + m) * HW_ + pos0 + lid;
#pragma unroll
            for (int ni = 0; ni < 4; ++ni)
                po[ni * 16] = acc[mi][ni][r] + bias;
        }
    }
}

extern "C" void kernel_launch(void* const* d_in, const int* in_sizes, int n_in,
                              void* d_out, int out_size, void* d_ws, size_t ws_size,
                              hipStream_t stream) {
    const float* x     = (const float*)d_in[0];
    const float* w_off = (const float*)d_in[1];
    const float* b_off = (const float*)d_in[2];
    const float* w_dcn = (const float*)d_in[3];
    const float* b_dcn = (const float*)d_in[4];
    float* out = (float*)d_out;

    // ws: off 1.81 | wA 1.18 | xT 12.85 | part 7.23 | V (chunked) MB
    const size_t offBytes  = (size_t)451584 * 4;
    const size_t wABytes   = (size_t)589824 * 2;
    const size_t xTBytes   = (size_t)B_ * HW_ * 256 * 2;
    const size_t partBytes = (size_t)4 * 451584 * 4;
    const size_t unitB     = (size_t)NKC * 64 * 32 * 2;
    float*          off  = (float*)d_ws;
    unsigned short* wA   = (unsigned short*)((char*)d_ws + offBytes);
    unsigned short* xT   = (unsigned short*)((char*)d_ws + offBytes + wABytes);
    float*          part = (float*)((char*)d_ws + offBytes + wABytes + xTBytes);
    unsigned short* V    = (unsigned short*)((char*)part + partBytes);

    size_t used  = offBytes + wABytes + xTBytes + partBytes;
    size_t avail = ws_size > used ? ws_size - used : 0;
    int upc = (int)(avail / unitB);
    if (upc > 392) upc = 392;
    if (upc < 1)  upc = 1;

    k_buildA <<<2304, 256, 0, stream>>>(w_dcn, wA);
    k_transx <<<1568, 256, 0, stream>>>(x, xT);
    k_offc1  <<<1568, 512, 0, stream>>>(x, w_off, part);
    k_offc2  <<<1764, 256, 0, stream>>>(part, b_off, off);
    for (int u0 = 0; u0 < 392; u0 += upc) {
        int n = 392 - u0 < upc ? 392 - u0 : upc;
        int nb = ((n + 7) / 8) * 16;
        k_gather<<<nb, 256, 0, stream>>>(xT, off, V, u0, n);
        k_gemm  <<<n, 256, 0, stream>>>(
            (const __bf16*)V, (const __bf16*)wA, b_dcn, out, u0, n);
    }
}

// Round 2
// 202.749 us; speedup vs baseline: 1.2431x; 1.1972x over previous
//
#include <hip/hip_runtime.h>

#define B_  8
#define C_  256
#define O_  256
#define H_  56
#define W_  56
#define HW_ 3136
#define KK_ 9
#define CK_ 2304   // C_*KK_
#define NKC 72     // K-chunks of 32

typedef __bf16    bf16x8 __attribute__((ext_vector_type(8)));
typedef float     f32x4  __attribute__((ext_vector_type(4)));

// async 16B/lane global->LDS: lds base wave-uniform; HW adds lane*16.
__device__ __forceinline__ void async16(const void* gsrc_lane, void* lds_uniform) {
    __builtin_amdgcn_global_load_lds(
        (const __attribute__((address_space(1))) unsigned int*)gsrc_lane,
        (__attribute__((address_space(3))) unsigned int*)lds_uniform, 16, 0, 0);
}

// XOR chunk swizzle: logical 16B-chunk q of row r stored at q ^ swz4(r).
__device__ __forceinline__ int swz4(int r) { return (r & 3) ^ ((r >> 2) & 3); }

__device__ __forceinline__ float blo(unsigned u) {
    return __builtin_bit_cast(float, u << 16);
}
__device__ __forceinline__ float bhi(unsigned u) {
    return __builtin_bit_cast(float, u & 0xffff0000u);
}
__device__ __forceinline__ unsigned pkbf(float lo, float hi) {
    unsigned short a = __builtin_bit_cast(unsigned short, (__bf16)lo);
    unsigned short b = __builtin_bit_cast(unsigned short, (__bf16)hi);
    return (unsigned)a | ((unsigned)b << 16);
}

__device__ __forceinline__ uint4 bilin4(uint4 c00, uint4 c01, uint4 c10, uint4 c11,
                                        float4 wg) {
    uint4 o;
    float lo_, hi_;
    lo_ = wg.x*blo(c00.x) + wg.y*blo(c01.x) + wg.z*blo(c10.x) + wg.w*blo(c11.x);
    hi_ = wg.x*bhi(c00.x) + wg.y*bhi(c01.x) + wg.z*bhi(c10.x) + wg.w*bhi(c11.x);
    o.x = pkbf(lo_, hi_);
    lo_ = wg.x*blo(c00.y) + wg.y*blo(c01.y) + wg.z*blo(c10.y) + wg.w*blo(c11.y);
    hi_ = wg.x*bhi(c00.y) + wg.y*bhi(c01.y) + wg.z*bhi(c10.y) + wg.w*bhi(c11.y);
    o.y = pkbf(lo_, hi_);
    lo_ = wg.x*blo(c00.z) + wg.y*blo(c01.z) + wg.z*blo(c10.z) + wg.w*blo(c11.z);
    hi_ = wg.x*bhi(c00.z) + wg.y*bhi(c01.z) + wg.z*bhi(c10.z) + wg.w*bhi(c11.z);
    o.z = pkbf(lo_, hi_);
    lo_ = wg.x*blo(c00.w) + wg.y*blo(c01.w) + wg.z*blo(c10.w) + wg.w*blo(c11.w);
    hi_ = wg.x*bhi(c00.w) + wg.y*bhi(c01.w) + wg.z*bhi(c10.w) + wg.w*bhi(c11.w);
    o.w = pkbf(lo_, hi_);
    return o;
}

// ---------------------------------------------------------------------------
// Kernel 1: wA[kc][m=256][32] bf16, tap-major K (gk=kc*32+kl -> tap=gk>>8,
// c=gk&255), XOR chunk swizzle baked into the global image. 1.18 MB.
// ---------------------------------------------------------------------------
__global__ __launch_bounds__(256) void k_buildA(const float* __restrict__ w,
                                                unsigned short* __restrict__ wA) {
    int d  = blockIdx.x * 256 + threadIdx.x;   // exact 2304*256
    int kc = d >> 13;
    int rd = d & 8191;
    int m  = rd >> 5;
    int pos = rd & 31;
    int q  = (pos >> 3) ^ swz4(m);
    int kl = q * 8 + (pos & 7);
    int gk = kc * 32 + kl;
    int tap = gk >> 8, c = gk & 255;
    __bf16 v = (__bf16)w[m * CK_ + c * KK_ + tap];
    wA[d] = __builtin_bit_cast(unsigned short, v);
}

// ---------------------------------------------------------------------------
// Kernel 2: x NCHW f32 -> xT NHWC bf16 (12.85 MB).
// ---------------------------------------------------------------------------
__global__ __launch_bounds__(256) void k_transx(const float* __restrict__ x,
                                                unsigned short* __restrict__ xT) {
    __shared__ float s[64][65];
    int bt   = blockIdx.x;            // 8 * 49 * 4
    int c64  = bt & 3;
    int hw64 = (bt >> 2) % 49;
    int b    = bt / 196;
    int tx = threadIdx.x & 63;
    int ty = threadIdx.x >> 6;
#pragma unroll
    for (int i = 0; i < 16; ++i)
        s[i * 4 + ty][tx] =
            x[((size_t)(b * 256 + c64 * 64 + i * 4 + ty)) * HW_ + hw64 * 64 + tx];
    __syncthreads();
#pragma unroll
    for (int i = 0; i < 16; ++i) {
        float v = s[tx][i * 4 + ty];
        xT[((size_t)b * HW_ + hw64 * 64 + i * 4 + ty) * 256 + c64 * 64 + tx] =
            __builtin_bit_cast(unsigned short, (__bf16)v);
    }
}

// ---------------------------------------------------------------------------
// Kernel 3a: offset conv partials.
// ---------------------------------------------------------------------------
__global__ __launch_bounds__(512) void k_offc1(const float* __restrict__ x,
                                               const float* __restrict__ w_off,
                                               float* __restrict__ part) {
    __shared__ float partial[8][64][18];      // 36864 B
    int t  = threadIdx.x;
    int p  = t & 63;
    int cg = __builtin_amdgcn_readfirstlane(t >> 6);
    int blk  = blockIdx.x;                    // 1568 = 392 units * 4 slices
    int sl   = blk & 3;
    int un   = blk >> 2;
    int b    = un / 49;
    int pos0 = (un % 49) * 64;
    int pos  = pos0 + p;
    int h = pos / W_;
    int w = pos % W_;
    const float* xb = x + (size_t)b * C_ * HW_;

    float acc[18];
#pragma unroll
    for (int i = 0; i < 18; ++i) acc[i] = 0.f;

    for (int cc = 0; cc < 8; ++cc) {
        int c = sl * 64 + cg * 8 + cc;
        const float* xp = xb + c * HW_;
        float v[9];
#pragma unroll
        for (int dh = -1; dh <= 1; ++dh)
#pragma unroll
            for (int dw = -1; dw <= 1; ++dw) {
                int hh = h + dh, ww = w + dw;
                bool ok = (hh >= 0) & (hh < H_) & (ww >= 0) & (ww < W_);
                v[(dh + 1) * 3 + dw + 1] = ok ? xp[hh * W_ + ww] : 0.f;
            }
        const float* wc = w_off + c * KK_;
#pragma unroll
        for (int oc = 0; oc < 18; ++oc) {
            const float* wr = wc + oc * CK_;  // wave-uniform -> s_load
#pragma unroll
            for (int k = 0; k < KK_; ++k)
                acc[oc] = fmaf(v[k], wr[k], acc[oc]);
        }
    }
#pragma unroll
    for (int oc = 0; oc < 18; ++oc) partial[cg][p][oc] = acc[oc];
    __syncthreads();

    float* po = part + (size_t)sl * (B_ * 18 * HW_);
    for (int e = t; e < 64 * 18; e += 512) {
        int oc = e >> 6;
        int pp = e & 63;
        float s = 0.f;
#pragma unroll
        for (int g = 0; g < 8; ++g) s += partial[g][pp][oc];
        po[((size_t)b * 18 + oc) * HW_ + pos0 + pp] = s;
    }
}

// ---------------------------------------------------------------------------
// Kernel 3b: sum 4 slices + bias -> off.
// ---------------------------------------------------------------------------
__global__ __launch_bounds__(256) void k_offc2(const float* __restrict__ part,
                                               const float* __restrict__ b_off,
                                               float* __restrict__ off) {
    int i = blockIdx.x * 256 + threadIdx.x;   // exact 451584
    const int NP = B_ * 18 * HW_;
    int oc = (i / HW_) % 18;
    off[i] = part[i] + part[i + NP] + part[i + 2 * NP] + part[i + 3 * NP]
           + b_off[oc];
}

// ---------------------------------------------------------------------------
// Kernel 4 (FUSED gather+GEMM): one block per unit (grid 392), 256 thr,
// M=256(O) x N=64(pos), K=2304 in 72 kc-stages of 32.
//   A path: 3-stage async16 pipeline from wA (wave-private slices, counted
//           waits, never vmcnt(0) mid-loop) - verbatim from round-0 gemm.
//   B path: produced IN-KERNEL per stage: 4 bilinear corner loads
//           (global->reg, issued at stage top, waited after the MFMA
//           cluster by the compiler), bilinear VALU, one swizzled
//           ds_write_b128 into a 2-stage LDS buffer; barrier publishes.
// Eliminates the 113 MB V write + ~58 MB V re-read of the split version.
// LDS: 48K(A) + 8K(B) + 18K(tables) = 74 KB -> 2 blocks/CU.
// ---------------------------------------------------------------------------
__device__ __forceinline__ void fstage(
    int s, int chNext, bool issueA, bool prod, bool reload,
    const char* xb, const char* gA0,
    __bf16 (*s_a)[8192], __bf16 (*s_b)[2048],
    int (*s_id)[64][4], float (*s_w)[64][4],
    int4& id, float4& wg,
    int n, int tc, int sc, int wv, int lid, int quad, int swz, int lo,
    f32x4 (&acc)[4][4]) {

    if (reload) {                       // tables for next tap ((s+1)>>3)
        int tp1 = (s + 1) >> 3;
        id = *(const int4*)s_id[tp1][n];
        wg = *(const float4*)s_w[tp1][n];
    }
    uint4 c00, c01, c10, c11;
    if (prod) {                         // corners for stage s+1 (reg-staged)
        const char* p = xb + chNext * 64 + tc * 16;
        c00 = *(const uint4*)(p + id.x);
        c01 = *(const uint4*)(p + id.y);
        c10 = *(const uint4*)(p + id.z);
        c11 = *(const uint4*)(p + id.w);
    }
    if (issueA) {                       // async A(s+2)
        const char* ga = gA0 + (size_t)(s + 2) * 16384;
        char* la = (char*)s_a[(s + 2) % 3];
#pragma unroll
        for (int j = 0; j < 4; ++j)
            async16(ga + wv * 4096 + j * 1024 + lo, la + wv * 4096 + j * 1024);
    }
    // Drain A(s): newest 12 = A(s+1)[4] + corners(s+1)[4] + A(s+2)[4].
    asm volatile("s_waitcnt vmcnt(12)" ::: "memory");

    const bf16x8* pa = (const bf16x8*)s_a[s % 3];
    const bf16x8* pb = (const bf16x8*)s_b[s & 1];
    bf16x8 af[4], bv[4];
#pragma unroll
    for (int mi = 0; mi < 4; ++mi)
        af[mi] = pa[(wv * 64 + mi * 16 + lid) * 4 + (quad ^ swz)];
#pragma unroll
    for (int ni = 0; ni < 4; ++ni)
        bv[ni] = pb[(ni * 16 + lid) * 4 + (quad ^ swz)];

    __builtin_amdgcn_s_setprio(1);
#pragma unroll
    for (int mi = 0; mi < 4; ++mi)
#pragma unroll
        for (int ni = 0; ni < 4; ++ni)
            acc[mi][ni] = __builtin_amdgcn_mfma_f32_16x16x32_bf16(
                af[mi], bv[ni], acc[mi][ni], 0, 0, 0);
    __builtin_amdgcn_s_setprio(0);

    if (prod) {                         // compiler emits the corner vmcnt here
        uint4 o = bilin4(c00, c01, c10, c11, wg);
        *(uint4*)((char*)s_b[(s & 1) ^ 1] + n * 64 + sc * 16) = o;
    }
    asm volatile("s_waitcnt lgkmcnt(0)" ::: "memory");
    __builtin_amdgcn_s_barrier();
    __builtin_amdgcn_sched_barrier(0);
}

__global__ __launch_bounds__(256, 2) void k_fused(
    const unsigned short* __restrict__ xT,
    const float* __restrict__ off,
    const __bf16* __restrict__ wA,
    const float* __restrict__ b_dcn,
    float* __restrict__ out) {

    __shared__ __bf16 s_a[3][8192];       // 48 KB: A kc-tile 256m x 32k
    __shared__ __bf16 s_b[2][2048];       //  8 KB: B kc-tile  64n x 32k
    __shared__ int    s_id[KK_][64][4];   //  9 KB
    __shared__ float  s_w [KK_][64][4];   //  9 KB

    int g    = blockIdx.x;                // 392 units
    int b    = g / 49;
    int pos0 = (g % 49) * 64;
    int t    = threadIdx.x;
    int lane = t & 63;
    int wv   = t >> 6;
    int lid  = lane & 15;
    int quad = lane >> 4;
    int swz  = swz4(lid);

    // --- bilinear tables (byte offsets into NHWC plane, 4 weights) ---
    for (int e = t; e < KK_ * 64; e += 256) {
        int k = e >> 6, n = e & 63;
        int pos = pos0 + n;
        int h = pos / W_, w = pos % W_;
        float dy = off[((size_t)b * 18 + 2 * k) * HW_ + pos];
        float dx = off[((size_t)b * 18 + 2 * k + 1) * HW_ + pos];
        float py = (float)(h + k / 3 - 1) + dy;
        float px = (float)(w + k % 3 - 1) + dx;
        float y0f = floorf(py), x0f = floorf(px);
        float fy = py - y0f, fx = px - x0f;
        int y0 = (int)y0f, x0 = (int)x0f;
        int y1 = y0 + 1,   x1 = x0 + 1;
        float oy0 = (y0 >= 0 && y0 < H_) ? 1.f : 0.f;
        float oy1 = (y1 >= 0 && y1 < H_) ? 1.f : 0.f;
        float ox0 = (x0 >= 0 && x0 < W_) ? 1.f : 0.f;
        float ox1 = (x1 >= 0 && x1 < W_) ? 1.f : 0.f;
        int y0c = min(max(y0, 0), H_ - 1), y1c = min(max(y1, 0), H_ - 1);
        int x0c = min(max(x0, 0), W_ - 1), x1c = min(max(x1, 0), W_ - 1);
        s_id[k][n][0] = (y0c * W_ + x0c) * 512;   // 256 ch * 2 B
        s_id[k][n][1] = (y0c * W_ + x1c) * 512;
        s_id[k][n][2] = (y1c * W_ + x0c) * 512;
        s_id[k][n][3] = (y1c * W_ + x1c) * 512;
        s_w[k][n][0] = (1.f - fy) * (1.f - fx) * oy0 * ox0;
        s_w[k][n][1] = (1.f - fy) * fx         * oy0 * ox1;
        s_w[k][n][2] = fy * (1.f - fx)         * oy1 * ox0;
        s_w[k][n][3] = fy * fx                 * oy1 * ox1;
    }
    __syncthreads();

    int n  = t >> 2;
    int tc = t & 3;
    int sc = tc ^ swz4(n);
    const char* xb  = (const char*)(xT + (size_t)b * HW_ * 256);
    const char* gA0 = (const char*)wA;
    int lo = lane * 16;

    f32x4 acc[4][4];
#pragma unroll
    for (int mi = 0; mi < 4; ++mi)
#pragma unroll
        for (int ni = 0; ni < 4; ++ni)
            acc[mi][ni] = (f32x4)(0.f);

    // ---- prologue: B(0) produced in-reg; A(0),A(1) async-issued ----
    int4   id = *(const int4*)s_id[0][n];
    float4 wg = *(const float4*)s_w[0][n];
    {
        const char* p = xb + tc * 16;             // ch1 = 0
        uint4 c00 = *(const uint4*)(p + id.x);
        uint4 c01 = *(const uint4*)(p + id.y);
        uint4 c10 = *(const uint4*)(p + id.z);
        uint4 c11 = *(const uint4*)(p + id.w);
#pragma unroll
        for (int ss = 0; ss < 2; ++ss) {
            const char* ga = gA0 + (size_t)ss * 16384;
            char* la = (char*)s_a[ss];
#pragma unroll
            for (int j = 0; j < 4; ++j)
                async16(ga + wv * 4096 + j * 1024 + lo, la + wv * 4096 + j * 1024);
        }
        uint4 o = bilin4(c00, c01, c10, c11, wg);
        *(uint4*)((char*)s_b[0] + n * 64 + sc * 16) = o;
    }
    asm volatile("s_waitcnt lgkmcnt(0)" ::: "memory");
    __builtin_amdgcn_s_barrier();
    __builtin_amdgcn_sched_barrier(0);

    // ---- main: 8 full tap-blocks (s = 0..63) ----
    for (int tap = 0; tap < 8; ++tap) {
        int s0 = tap * 8;
#pragma unroll
        for (int i = 0; i < 8; ++i)
            fstage(s0 + i, (i + 1) & 7, true, true, i == 7,
                   xb, gA0, s_a, s_b, s_id, s_w, id, wg,
                   n, tc, sc, wv, lid, quad, swz, lo, acc);
    }
    // ---- tail tap-block (s = 64..71) ----
#pragma unroll
    for (int i = 0; i < 8; ++i)
        fstage(64 + i, (i + 1) & 7, i < 6, i < 7, false,
               xb, gA0, s_a, s_b, s_id, s_w, id, wg,
               n, tc, sc, wv, lid, quad, swz, lo, acc);

    // ---- epilogue: bias + store. D: col(n)=lane&15, row(m)=quad*4+reg ----
#pragma unroll
    for (int mi = 0; mi < 4; ++mi) {
#pragma unroll
        for (int r = 0; r < 4; ++r) {
            int m = wv * 64 + mi * 16 + quad * 4 + r;
            float bias = b_dcn[m];
            float* po = out + ((size_t)b * O_ + m) * HW_ + pos0 + lid;
#pragma unroll
            for (int ni = 0; ni < 4; ++ni)
                po[ni * 16] = acc[mi][ni][r] + bias;
        }
    }
}

extern "C" void kernel_launch(void* const* d_in, const int* in_sizes, int n_in,
                              void* d_out, int out_size, void* d_ws, size_t ws_size,
                              hipStream_t stream) {
    const float* x     = (const float*)d_in[0];
    const float* w_off = (const float*)d_in[1];
    const float* b_off = (const float*)d_in[2];
    const float* w_dcn = (const float*)d_in[3];
    const float* b_dcn = (const float*)d_in[4];
    float* out = (float*)d_out;

    // ws: off 1.81 | wA 1.18 | xT 12.85 | part 7.23 MB  (V eliminated)
    const size_t offBytes  = (size_t)451584 * 4;
    const size_t wABytes   = (size_t)589824 * 2;
    const size_t xTBytes   = (size_t)B_ * HW_ * 256 * 2;
    float*          off  = (float*)d_ws;
    unsigned short* wA   = (unsigned short*)((char*)d_ws + offBytes);
    unsigned short* xT   = (unsigned short*)((char*)d_ws + offBytes + wABytes);
    float*          part = (float*)((char*)d_ws + offBytes + wABytes + xTBytes);

    k_buildA <<<2304, 256, 0, stream>>>(w_dcn, wA);
    k_transx <<<1568, 256, 0, stream>>>(x, xT);
    k_offc1  <<<1568, 512, 0, stream>>>(x, w_off, part);
    k_offc2  <<<1764, 256, 0, stream>>>(part, b_off, off);
    k_fused  <<<392,  256, 0, stream>>>(xT, off, (const __bf16*)wA, b_dcn, out);
}